// Round 11
// baseline (483.776 us; speedup 1.0000x reference)
//
#include <hip/hip_runtime.h>

// embeddings [B=2][F=32][N=2359296] f32, labels [B][N] i32, prototypes [12][32] f32
// sums[c][f] = sum_n onehot[c][n] * emb[f][n]  ==  mfma(A=onehot, B=emb)
// mfma_f32_16x16x32_bf16 layout: lane l holds outdim=l&15, k=8*(l>>4)+j (j=0..7);
// C/D: col=l&15, row=(l>>4)*4+reg.
// Ledger: R4/R8=124.2 (reg loads; BEST) | R5=205 spill | R7=158 nt | R9=157 remap
//         R10=177 LDS-stage. All DRAM-pattern alternatives lose -> R4 body frozen.
// This round: fuse finalize via last-block-done (saves 1 dispatch + graph gap).
#define B_        2
#define F_        32
#define C_        12
#define NVOX      2359296L
#define THREADS   256
#define WAVE_SPAN 576                  // voxels per wave
#define BLOCK_SPAN (WAVE_SPAN * 4)     // 2304
#define NBLK      1024                 // x-dim; 2048 total blocks
#define NBLK_TOT  (NBLK * B_)
#define KSTEPS    (WAVE_SPAN / 32)     // 18 mfma K-steps per wave
#define NREP      16                   // replicated global accumulators

typedef __attribute__((ext_vector_type(8))) short short8;   // 8 bf16 (4 VGPRs)
typedef __attribute__((ext_vector_type(4))) float f32x4;

union ABu { short8 s; __bf16 h[8]; unsigned u[4]; };

__global__ __launch_bounds__(THREADS)
void accum_fused(const float* __restrict__ emb,
                 const int*   __restrict__ labels,
                 const float* __restrict__ proto,
                 float*       __restrict__ out,      // [C*F]
                 float*       __restrict__ g_sums,   // [NREP][B][C*F]
                 float*       __restrict__ g_cnts,   // [NREP][B][C]
                 unsigned*    __restrict__ g_done) { // [1]
    const int b    = blockIdx.y;
    const int tid  = threadIdx.x;
    const int wv   = tid >> 6;
    const int lane = tid & 63;
    const int fcol = lane & 15;        // feature col (and one-hot class row)
    const int kgrp = lane >> 4;        // 0..3, k-base = kgrp*8
    const int rep  = blockIdx.x & (NREP - 1);

    const long n0 = (long)blockIdx.x * BLOCK_SPAN + (long)wv * WAVE_SPAN + (kgrp << 3);

    const int*   lab = labels + (long)b * NVOX + n0;
    const float* e0  = emb + (long)(b * F_ + fcol) * NVOX + n0;   // features 0..15
    const float* e1  = e0 + 16L * NVOX;                           // features 16..31

    ABu ones;
#pragma unroll
    for (int p = 0; p < 4; ++p) ones.u[p] = 0x3F803F80u;          // bf16 1.0 pairs

    f32x4 acc0 = {0.f, 0.f, 0.f, 0.f};   // sums, features 0..15
    f32x4 acc1 = {0.f, 0.f, 0.f, 0.f};   // sums, features 16..31
    f32x4 acc2 = {0.f, 0.f, 0.f, 0.f};   // counts

#pragma unroll 2
    for (int s = 0; s < KSTEPS; ++s) {
        int4 L0 = *(const int4*)(lab);
        int4 L1 = *(const int4*)(lab + 4);
        float4 v00 = *(const float4*)(e0);
        float4 v01 = *(const float4*)(e0 + 4);
        float4 v10 = *(const float4*)(e1);
        float4 v11 = *(const float4*)(e1 + 4);

        // A fragment: onehot[row=fcol][k] as bf16 {0,1}
        ABu a;
        {
            const int r = fcol;
            unsigned m0 = (min(L0.x, 11) == r) ? 0x3F80u : 0u;
            unsigned m1 = (min(L0.y, 11) == r) ? 0x3F80u : 0u;
            unsigned m2 = (min(L0.z, 11) == r) ? 0x3F80u : 0u;
            unsigned m3 = (min(L0.w, 11) == r) ? 0x3F80u : 0u;
            unsigned m4 = (min(L1.x, 11) == r) ? 0x3F80u : 0u;
            unsigned m5 = (min(L1.y, 11) == r) ? 0x3F80u : 0u;
            unsigned m6 = (min(L1.z, 11) == r) ? 0x3F80u : 0u;
            unsigned m7 = (min(L1.w, 11) == r) ? 0x3F80u : 0u;
            a.u[0] = m0 | (m1 << 16);
            a.u[1] = m2 | (m3 << 16);
            a.u[2] = m4 | (m5 << 16);
            a.u[3] = m6 | (m7 << 16);
        }

        // B fragments: f32 -> bf16 (RNE via v_cvt_pk_bf16_f32)
        ABu b0, b1;
        b0.h[0] = (__bf16)v00.x; b0.h[1] = (__bf16)v00.y;
        b0.h[2] = (__bf16)v00.z; b0.h[3] = (__bf16)v00.w;
        b0.h[4] = (__bf16)v01.x; b0.h[5] = (__bf16)v01.y;
        b0.h[6] = (__bf16)v01.z; b0.h[7] = (__bf16)v01.w;
        b1.h[0] = (__bf16)v10.x; b1.h[1] = (__bf16)v10.y;
        b1.h[2] = (__bf16)v10.z; b1.h[3] = (__bf16)v10.w;
        b1.h[4] = (__bf16)v11.x; b1.h[5] = (__bf16)v11.y;
        b1.h[6] = (__bf16)v11.z; b1.h[7] = (__bf16)v11.w;

        acc0 = __builtin_amdgcn_mfma_f32_16x16x32_bf16(a.s, b0.s,   acc0, 0, 0, 0);
        acc1 = __builtin_amdgcn_mfma_f32_16x16x32_bf16(a.s, b1.s,   acc1, 0, 0, 0);
        acc2 = __builtin_amdgcn_mfma_f32_16x16x32_bf16(a.s, ones.s, acc2, 0, 0, 0);

        lab += 32; e0 += 32; e1 += 32;
    }

    // ---- block reduction: LDS atomics (distinct addresses within a wave) ----
    __shared__ float lsum[16 * 32];
    __shared__ float lcnt[16];
    __shared__ int   is_last;
    for (int i = tid; i < 16 * 32; i += THREADS) lsum[i] = 0.f;
    if (tid < 16) lcnt[tid] = 0.f;
    __syncthreads();

#pragma unroll
    for (int r = 0; r < 4; ++r) {
        const int c = (kgrp << 2) + r;          // D row = class
        atomicAdd(&lsum[c * 32 + fcol],      acc0[r]);
        atomicAdd(&lsum[c * 32 + 16 + fcol], acc1[r]);
    }
    if (fcol == 0) {
#pragma unroll
        for (int r = 0; r < 4; ++r) atomicAdd(&lcnt[(kgrp << 2) + r], acc2[r]);
    }
    __syncthreads();

    // flush to replicated global accumulators (rep = blockIdx.x & 15)
    float* gs = g_sums + ((long)rep * B_ + b) * (C_ * F_);
    float* gc = g_cnts + ((long)rep * B_ + b) * C_;
    for (int i = tid; i < C_ * F_; i += THREADS)
        atomicAdd(&gs[i], lsum[i]);
    if (tid < C_)
        atomicAdd(&gc[tid], lcnt[tid]);

    // ---- last-block-done finalize (replaces the second dispatch) ----
    __threadfence();                      // make this block's flush visible
    if (tid == 0) {
        unsigned prev = atomicAdd(g_done, 1u);
        is_last = (prev == (unsigned)(NBLK_TOT - 1));
    }
    __syncthreads();
    if (!is_last) return;
    __threadfence();                      // acquire: all flushes visible

    for (int idx = tid; idx < C_ * F_; idx += THREADS) {
        const int c = idx / F_;
        float p = proto[idx];
#pragma unroll
        for (int bb = 0; bb < B_; ++bb) {
            float cnt = 0.f, s = 0.f;
#pragma unroll
            for (int rp = 0; rp < NREP; ++rp) {
                s   += g_sums[((long)rp * B_ + bb) * (C_ * F_) + idx];
                cnt += g_cnts[((long)rp * B_ + bb) * C_ + c];
            }
            if (cnt > 0.f) p = 0.9f * p + 0.1f * (s / cnt);
        }
        out[idx] = p;
    }
}

extern "C" void kernel_launch(void* const* d_in, const int* in_sizes, int n_in,
                              void* d_out, int out_size, void* d_ws, size_t ws_size,
                              hipStream_t stream) {
    const float* emb    = (const float*)d_in[0];
    const int*   labels = (const int*)d_in[1];
    const float* proto  = (const float*)d_in[2];
    float*       out    = (float*)d_out;

    float*    g_sums = (float*)d_ws;                       // NREP*B*C*F floats
    float*    g_cnts = g_sums + NREP * B_ * C_ * F_;       // NREP*B*C floats
    unsigned* g_done = (unsigned*)(g_cnts + NREP * B_ * C_);

    (void)hipMemsetAsync(d_ws, 0,
        (size_t)(NREP * B_ * (C_ * F_ + C_)) * sizeof(float) + sizeof(unsigned),
        stream);

    dim3 grid(NBLK, B_);
    accum_fused<<<grid, THREADS, 0, stream>>>(emb, labels, proto, out,
                                              g_sums, g_cnts, g_done);
}

// Round 12
// 124.297 us; speedup vs baseline: 3.8921x; 3.8921x over previous
//
#include <hip/hip_runtime.h>

// embeddings [B=2][F=32][N=2359296] f32, labels [B][N] i32, prototypes [12][32] f32
// sums[c][f] = sum_n onehot[c][n] * emb[f][n]  ==  mfma(A=onehot, B=emb)
// mfma_f32_16x16x32_bf16 layout: lane l holds outdim=l&15, k=8*(l>>4)+j (j=0..7);
// C/D: col=l&15, row=(l>>4)*4+reg.
// Ledger: R4/R8=124.2 (BEST, this source) | R5=205 spill | R7=158 nt | R9=157 remap
//         R10=177 LDS-stage | R11=484 fused-finalize (regalloc flipped to 48 VGPR,
//         serialized loads -> latency-bound; epilogue MUST stay a separate kernel).
// This round: exact revert to R8.
#define B_        2
#define F_        32
#define C_        12
#define NVOX      2359296L
#define THREADS   256
#define WAVE_SPAN 576                  // voxels per wave
#define BLOCK_SPAN (WAVE_SPAN * 4)     // 2304
#define NBLK      1024                 // 2048 total blocks
#define KSTEPS    (WAVE_SPAN / 32)     // 18 mfma K-steps per wave
#define NREP      16                   // replicated global accumulators

typedef __attribute__((ext_vector_type(8))) short short8;   // 8 bf16 (4 VGPRs)
typedef __attribute__((ext_vector_type(4))) float f32x4;

union ABu { short8 s; __bf16 h[8]; unsigned u[4]; };

__global__ __launch_bounds__(THREADS, 4)   // min 4 waves/EU -> VGPR<=128 (R8-neutral)
void accum_mfma(const float* __restrict__ emb,
                const int*   __restrict__ labels,
                float*       __restrict__ g_sums,   // [NREP][B][C*F]
                float*       __restrict__ g_cnts) { // [NREP][B][C]
    const int b    = blockIdx.y;
    const int tid  = threadIdx.x;
    const int wv   = tid >> 6;
    const int lane = tid & 63;
    const int fcol = lane & 15;        // feature col (and one-hot class row)
    const int kgrp = lane >> 4;        // 0..3, k-base = kgrp*8
    const int rep  = blockIdx.x & (NREP - 1);

    const long n0 = (long)blockIdx.x * BLOCK_SPAN + (long)wv * WAVE_SPAN + (kgrp << 3);

    const int*   lab = labels + (long)b * NVOX + n0;
    const float* e0  = emb + (long)(b * F_ + fcol) * NVOX + n0;   // features 0..15
    const float* e1  = e0 + 16L * NVOX;                           // features 16..31

    ABu ones;
#pragma unroll
    for (int p = 0; p < 4; ++p) ones.u[p] = 0x3F803F80u;          // bf16 1.0 pairs

    f32x4 acc0 = {0.f, 0.f, 0.f, 0.f};   // sums, features 0..15
    f32x4 acc1 = {0.f, 0.f, 0.f, 0.f};   // sums, features 16..31
    f32x4 acc2 = {0.f, 0.f, 0.f, 0.f};   // counts

#pragma unroll 2
    for (int s = 0; s < KSTEPS; ++s) {
        // 8 labels for this lane's k-slots (16-lane groups share -> one transaction)
        int4 L0 = *(const int4*)(lab);
        int4 L1 = *(const int4*)(lab + 4);
        // 8 consecutive voxels of this lane's two features
        float4 v00 = *(const float4*)(e0);
        float4 v01 = *(const float4*)(e0 + 4);
        float4 v10 = *(const float4*)(e1);
        float4 v11 = *(const float4*)(e1 + 4);

        // A fragment: onehot[row=fcol][k] as bf16 {0,1}
        ABu a;
        {
            const int r = fcol;
            unsigned m0 = (min(L0.x, 11) == r) ? 0x3F80u : 0u;
            unsigned m1 = (min(L0.y, 11) == r) ? 0x3F80u : 0u;
            unsigned m2 = (min(L0.z, 11) == r) ? 0x3F80u : 0u;
            unsigned m3 = (min(L0.w, 11) == r) ? 0x3F80u : 0u;
            unsigned m4 = (min(L1.x, 11) == r) ? 0x3F80u : 0u;
            unsigned m5 = (min(L1.y, 11) == r) ? 0x3F80u : 0u;
            unsigned m6 = (min(L1.z, 11) == r) ? 0x3F80u : 0u;
            unsigned m7 = (min(L1.w, 11) == r) ? 0x3F80u : 0u;
            a.u[0] = m0 | (m1 << 16);
            a.u[1] = m2 | (m3 << 16);
            a.u[2] = m4 | (m5 << 16);
            a.u[3] = m6 | (m7 << 16);
        }

        // B fragments: emb cast to bf16 (RNE via v_cvt_pk_bf16_f32)
        ABu b0, b1;
        b0.h[0] = (__bf16)v00.x; b0.h[1] = (__bf16)v00.y;
        b0.h[2] = (__bf16)v00.z; b0.h[3] = (__bf16)v00.w;
        b0.h[4] = (__bf16)v01.x; b0.h[5] = (__bf16)v01.y;
        b0.h[6] = (__bf16)v01.z; b0.h[7] = (__bf16)v01.w;
        b1.h[0] = (__bf16)v10.x; b1.h[1] = (__bf16)v10.y;
        b1.h[2] = (__bf16)v10.z; b1.h[3] = (__bf16)v10.w;
        b1.h[4] = (__bf16)v11.x; b1.h[5] = (__bf16)v11.y;
        b1.h[6] = (__bf16)v11.z; b1.h[7] = (__bf16)v11.w;

        acc0 = __builtin_amdgcn_mfma_f32_16x16x32_bf16(a.s, b0.s,   acc0, 0, 0, 0);
        acc1 = __builtin_amdgcn_mfma_f32_16x16x32_bf16(a.s, b1.s,   acc1, 0, 0, 0);
        acc2 = __builtin_amdgcn_mfma_f32_16x16x32_bf16(a.s, ones.s, acc2, 0, 0, 0);

        lab += 32; e0 += 32; e1 += 32;
    }

    // ---- block reduction: LDS atomics (distinct addresses within a wave) ----
    __shared__ float lsum[16 * 32];
    __shared__ float lcnt[16];
    for (int i = tid; i < 16 * 32; i += THREADS) lsum[i] = 0.f;
    if (tid < 16) lcnt[tid] = 0.f;
    __syncthreads();

#pragma unroll
    for (int r = 0; r < 4; ++r) {
        const int c = (kgrp << 2) + r;          // D row = class
        atomicAdd(&lsum[c * 32 + fcol],      acc0[r]);
        atomicAdd(&lsum[c * 32 + 16 + fcol], acc1[r]);
    }
    if (fcol == 0) {
#pragma unroll
        for (int r = 0; r < 4; ++r) atomicAdd(&lcnt[(kgrp << 2) + r], acc2[r]);
    }
    __syncthreads();

    // flush to replicated global accumulators (rep = blockIdx.x & 15)
    float* gs = g_sums + ((long)rep * B_ + b) * (C_ * F_);
    float* gc = g_cnts + ((long)rep * B_ + b) * C_;
    for (int i = tid; i < C_ * F_; i += THREADS)
        atomicAdd(&gs[i], lsum[i]);
    if (tid < C_)
        atomicAdd(&gc[tid], lcnt[tid]);
}

__global__ void finalize_kernel(const float* __restrict__ g_sums,
                                const float* __restrict__ g_cnts,
                                const float* __restrict__ proto,
                                float*       __restrict__ out) {
    const int idx = threadIdx.x;               // 0..383 = c*F + f
    if (idx >= C_ * F_) return;
    const int c = idx / F_;
    float p = proto[idx];
#pragma unroll
    for (int b = 0; b < B_; ++b) {
        float cnt = 0.f, s = 0.f;
#pragma unroll
        for (int rep = 0; rep < NREP; ++rep) {
            s   += g_sums[((long)rep * B_ + b) * (C_ * F_) + idx];
            cnt += g_cnts[((long)rep * B_ + b) * C_ + c];
        }
        if (cnt > 0.f) p = 0.9f * p + 0.1f * (s / cnt);
    }
    out[idx] = p;
}

extern "C" void kernel_launch(void* const* d_in, const int* in_sizes, int n_in,
                              void* d_out, int out_size, void* d_ws, size_t ws_size,
                              hipStream_t stream) {
    const float* emb    = (const float*)d_in[0];
    const int*   labels = (const int*)d_in[1];
    const float* proto  = (const float*)d_in[2];
    float*       out    = (float*)d_out;

    float* g_sums = (float*)d_ws;                      // NREP*B*C*F floats
    float* g_cnts = g_sums + NREP * B_ * C_ * F_;      // NREP*B*C floats

    (void)hipMemsetAsync(d_ws, 0,
                   (size_t)(NREP * B_ * (C_ * F_ + C_)) * sizeof(float), stream);

    dim3 grid(NBLK, B_);
    accum_mfma<<<grid, THREADS, 0, stream>>>(emb, labels, g_sums, g_cnts);
    finalize_kernel<<<1, C_ * F_, 0, stream>>>(g_sums, g_cnts, proto, out);
}